// Round 4
// baseline (125.816 us; speedup 1.0000x reference)
//
#include <hip/hip_runtime.h>

// Problem constants (B=4, C=64, H=W=128, O=64, K=3, stride=1, pad=1, dil=1)
#define B_   4
#define C_   64
#define O_   64
#define H_   128
#define W_   128
#define HW_  (H_ * W_)
#define KK_  9
#define M_   18          // 2*KK offset channels

typedef short  short8  __attribute__((ext_vector_type(8)));
typedef float  floatx4 __attribute__((ext_vector_type(4)));
typedef float  float2v __attribute__((ext_vector_type(2)));
typedef unsigned int   uint4v   __attribute__((ext_vector_type(4)));
typedef unsigned short ushort8v __attribute__((ext_vector_type(8)));

static __device__ __forceinline__ unsigned short f2bf(float f) {
    unsigned int u = __float_as_uint(f);
    u += 0x7FFFu + ((u >> 16) & 1u);     // round-to-nearest-even
    return (unsigned short)(u >> 16);
}
// unpack a 32-bit word holding 2 bf16 -> v2f32
static __device__ __forceinline__ float2v bf2x(unsigned int q) {
    float2v r;
    r.x = __uint_as_float(q << 16);
    r.y = __uint_as_float(q & 0xFFFF0000u);
    return r;
}
// guaranteed packed fp32 math (VOP3P) -- no scalarization ambiguity
static __device__ __forceinline__ float2v pk_mul(float2v a, float2v b) {
    float2v d;
    asm("v_pk_mul_f32 %0, %1, %2" : "=v"(d) : "v"(a), "v"(b));
    return d;
}
static __device__ __forceinline__ float2v pk_fma(float2v a, float2v b, float2v c) {
    float2v d;
    asm("v_pk_fma_f32 %0, %1, %2, %3" : "=v"(d) : "v"(a), "v"(b), "v"(c));
    return d;
}

// ---------------------------------------------------------------------------
// Prep (single launch):
//  blocks [0,1024):     x -> xT[b][y][x][c64] bf16 (pixel-contiguous 128 B),
//                       half-row per block. LDS transpose tile T has row
//                       stride 70 ushorts (35 words, odd) -> the column write
//                       T[xc][c] is 2-way (free) instead of 8-way conflicted.
//  blocks [1024,1042):  wtbf  = main-conv B-fragments in lane order
//                       layout: element ((cks*4 + ot)*64 + lane)*8
//  blocks [1042,1051):  owtbf = offset-conv B-fragments in lane order
// ---------------------------------------------------------------------------
__global__ __launch_bounds__(256) void prep(
        const float* __restrict__ x, const float* __restrict__ w,
        const float* __restrict__ ow, unsigned short* __restrict__ xT,
        unsigned short* __restrict__ wtbf, unsigned short* __restrict__ owtbf) {
    const int blk = blockIdx.x;
    if (blk < 1024) {
        __shared__ unsigned short T[64][70];    // stride 35 words (odd) -> no
        const int tid  = threadIdx.x;           // bank conflicts on col writes
        const int half = blk & 1;
        const int y    = (blk >> 1) & (H_ - 1);
        const int b    = blk >> 8;
        const float* xby = x + (size_t)b * C_ * HW_ + y * W_ + half * 64;
        for (int i = tid; i < 64 * 64; i += 256) {
            const int c = i >> 6, xc = i & 63;
            T[xc][c] = f2bf(xby[(size_t)c * HW_ + xc]);
        }
        __syncthreads();
        // write pixel-contiguous: xT[(b*HW + y*W + x)*64 + c]
        unsigned short* dst = xT + ((size_t)b * HW_ + y * W_ + half * 64) * 64;
        for (int j = tid; j < 512; j += 256) {
            const int x8 = j >> 3, c8 = j & 7;
            uint4v pk;
            #pragma unroll
            for (int k = 0; k < 4; ++k)
                pk[k] = *(const unsigned int*)&T[x8][c8 * 8 + k * 2];
            *(uint4v*)&dst[x8 * 64 + c8 * 8] = pk;
        }
    } else if (blk < 1042) {
        // wtbf: i = (cks*4 + ot)*64 + lane
        const int i = (blk - 1024) * 256 + threadIdx.x;
        const int lane = i & 63, rest = i >> 6;
        const int ot = rest & 3, cks = rest >> 2;      // cks = tap*2+chalf
        const int chunk = cks / 6, ks = cks % 6;
        const int o = ot * 16 + (lane & 15);
        const int kbase = chunk * 192 + ks * 32 + (lane >> 4) * 8;
        ushort8v pk;
        #pragma unroll
        for (int j = 0; j < 8; ++j) {
            const int k = kbase + j;                   // k = tap*64 + c
            pk[j] = f2bf(w[o * 576 + (k & 63) * 9 + (k >> 6)]);
        }
        *(ushort8v*)&wtbf[(size_t)i * 8] = pk;
    } else {
        // owtbf: i = (tks*2 + tile)*64 + lane
        const int i = (blk - 1042) * 256 + threadIdx.x;
        const int lane = i & 63, rest = i >> 6;
        const int tile = rest & 1, tks = rest >> 1;    // tks = tap*2+ks
        const int tap = tks >> 1, ks = tks & 1;
        const int m = tile * 16 + (lane & 15);
        const int cb = ks * 32 + (lane >> 4) * 8;
        ushort8v pk;
        #pragma unroll
        for (int j = 0; j < 8; ++j)
            pk[j] = (m < M_) ? f2bf(ow[m * 576 + (cb + j) * 9 + tap])
                             : (unsigned short)0;
        *(ushort8v*)&owtbf[(size_t)i * 8] = pk;
    }
}

// ---------------------------------------------------------------------------
// Fused deformable conv. Block = 64-px row segment, 4 waves; wave w owns
// px-tile [16w,16w+16):
//   A1: stage P[3][66][72] from pixel-contiguous xT (coalesced) -> barrier
//   A2: wave computes its tile's 18 offsets via MFMA; offs (+ob) to
//       wave-private offs[w][18][16]                            -> barrier
//   B (3 chunks x 3 unrolled taps, ZERO barriers, ZERO shared-LDS):
//       3 taps in flight -> up to 24 outstanding b128 gather loads per wave
//       (round-3's unroll-1 was latency-bound at 54us: MfmaUtil 4.8,
//       VALUBusy 21, occ 31 -- all pipes idle). Packed-fp32 bilinear
//       (forced v_pk_fma), pack via +0x8000 + v_perm, 4 MFMAs per chalf
//       vs lane-ordered wtbf.
//   Epilogue: wave-private staging in the (dead) P union -> coalesced stores.
// XCD banding (blockIdx%8 = XCD): XCD x owns rows [16x,16x+16) -> xT slice
// L2-resident per XCD.
// ---------------------------------------------------------------------------
__global__ __launch_bounds__(256, 4) void dcn_fused(
        const unsigned short* __restrict__ xT,
        const unsigned short* __restrict__ owtbf, const float* __restrict__ ob,
        const unsigned short* __restrict__ wtbf, const float* __restrict__ bias,
        float* __restrict__ out) {
    __shared__ union {
        unsigned short P[3][66][72];             // 28512 B (phase A)
        float ep[4][64][17];                     // 17408 B (epilogue, per wave)
    } u;
    __shared__ float offs[4][M_][16];            // 4608 B (wave-private)

    const int tid    = threadIdx.x;
    const int lane   = tid & 63;
    const int wslot  = __builtin_amdgcn_readfirstlane(tid >> 6);
    const int lane15 = lane & 15;
    const int quad   = lane >> 4;

    // XCD-banded remap (g%8 = XCD): XCD x -> rows [16x,16x+16), all b/half
    const int g    = blockIdx.x;
    const int xcd  = g & 7;
    const int slot = g >> 3;
    const int ho   = xcd * 16 + (slot >> 3);
    const int b    = (slot >> 1) & 3;
    const int wo_base = (slot & 1) << 6;

    const unsigned short* xTb = xT + (size_t)b * HW_ * 64;

    // ---------------- Phase A1: stage 3 x-rows into P from xT ----------------
    // P[ky][r][c] = x[c][ho-1+ky][wo_base + r - 1],  r in [0,66)
    #pragma unroll
    for (int ky = 0; ky < 3; ++ky) {
        const int y  = ho - 1 + ky;
        const bool yv = (unsigned)y < (unsigned)H_;
        const unsigned short* src = xTb + (size_t)y * W_ * 64;
        for (int j = tid; j < 66 * 8; j += 256) {
            const int r = j >> 3, c8 = j & 7;
            const int cx = wo_base + r - 1;
            ushort8v p0 = {0, 0, 0, 0, 0, 0, 0, 0};
            if (yv && (unsigned)cx < (unsigned)W_)
                p0 = *(const ushort8v*)&src[cx * 64 + c8 * 8];
            *(ushort8v*)&u.P[ky][r][c8 * 8] = p0;
        }
    }
    __syncthreads();

    // ---------------- Phase A2: MFMA offset conv ----------------
    floatx4 oa0 = (floatx4){0.f, 0.f, 0.f, 0.f};
    floatx4 oa1 = (floatx4){0.f, 0.f, 0.f, 0.f};
    {
        const int pxt = wslot;
        #pragma unroll
        for (int ky = 0; ky < 3; ++ky) {
            #pragma unroll
            for (int kx = 0; kx < 3; ++kx) {
                const int tap = ky * 3 + kx;
                #pragma unroll
                for (int ks = 0; ks < 2; ++ks) {
                    const int kk = ks * 32 + quad * 8;
                    const short8 af =
                        *(const short8*)&u.P[ky][pxt * 16 + lane15 + kx][kk];
                    const int fb = ((tap * 2 + ks) * 2) * 64 + lane;
                    const short8 bf0 = *(const short8*)&owtbf[(size_t)fb * 8];
                    const short8 bf1 =
                        *(const short8*)&owtbf[(size_t)(fb + 64) * 8];
                    oa0 = __builtin_amdgcn_mfma_f32_16x16x32_bf16(af, bf0, oa0, 0, 0, 0);
                    oa1 = __builtin_amdgcn_mfma_f32_16x16x32_bf16(af, bf1, oa1, 0, 0, 0);
                }
            }
        }
    }
    // Wave-private offsets (+ offset-conv bias folded in)
    {
        const float ob0 = ob[lane15];
        #pragma unroll
        for (int r = 0; r < 4; ++r) oa0[r] += ob0;
        *(floatx4*)&offs[wslot][lane15][quad * 4] = oa0;
        if (lane15 < 2) {
            const float ob1 = ob[16 + lane15];
            #pragma unroll
            for (int r = 0; r < 4; ++r) oa1[r] += ob1;
            *(floatx4*)&offs[wslot][16 + lane15][quad * 4] = oa1;
        }
    }
    __syncthreads();   // all P reads done -> epilogue may overwrite the union

    // ---------------- Phase B: register-direct A-frags + MFMA ---------------
    const int pxg = wslot * 16 + lane15;   // px within the 64-px segment
    floatx4 acc[4];                        // o-tiles 0..3
    #pragma unroll
    for (int t = 0; t < 4; ++t) acc[t] = (floatx4){0.f, 0.f, 0.f, 0.f};

    for (int chunk = 0; chunk < 3; ++chunk) {
        #pragma unroll
        for (int tl = 0; tl < 3; ++tl) {
            const int k  = chunk * 3 + tl;     // global tap 0..8
            const int ky = k / 3, kx = k - ky * 3;
            // geometry once per tap (lane = its own pixel)
            const float offy = offs[wslot][2 * k][lane15];
            const float offx = offs[wslot][2 * k + 1][lane15];
            const float py  = (float)(ho - 1 + ky) + offy;
            const float pxx = (float)(wo_base - 1 + kx + pxg) + offx;
            const float fy = floorf(py), fx = floorf(pxx);
            const int y0 = (int)fy, x0 = (int)fx;
            const int y1 = y0 + 1,  x1 = x0 + 1;
            const float wy1 = py - fy,  wy0 = 1.f - wy1;
            const float wx1 = pxx - fx, wx0 = 1.f - wx1;
            const bool y0v = (unsigned)y0 < (unsigned)H_;
            const bool y1v = (unsigned)y1 < (unsigned)H_;
            const bool x0v = (unsigned)x0 < (unsigned)W_;
            const bool x1v = (unsigned)x1 < (unsigned)W_;
            const float w00 = (y0v && x0v) ? wy0 * wx0 : 0.f;
            const float w01 = (y0v && x1v) ? wy0 * wx1 : 0.f;
            const float w10 = (y1v && x0v) ? wy1 * wx0 : 0.f;
            const float w11 = (y1v && x1v) ? wy1 * wx1 : 0.f;
            const float2v w00_2 = {w00, w00};
            const float2v w01_2 = {w01, w01};
            const float2v w10_2 = {w10, w10};
            const float2v w11_2 = {w11, w11};
            const int ry0 = min(max(y0, 0), H_ - 1);
            const int ry1 = min(max(y1, 0), H_ - 1);
            const int cx0 = min(max(x0, 0), W_ - 1);
            const int cx1 = min(max(x1, 0), W_ - 1);
            const int a00 = (ry0 * W_ + cx0) * 64;   // ushort index of px base
            const int a01 = (ry0 * W_ + cx1) * 64;
            const int a10 = (ry1 * W_ + cx0) * 64;
            const int a11 = (ry1 * W_ + cx1) * 64;
            #pragma unroll
            for (int chalf = 0; chalf < 2; ++chalf) {
                // lane's channel octet; both chalf hit the SAME 128B px line
                const unsigned short* xp = xTb + chalf * 32 + quad * 8;
                const uint4v q00 = *(const uint4v*)&xp[a00];
                const uint4v q01 = *(const uint4v*)&xp[a01];
                const uint4v q10 = *(const uint4v*)&xp[a10];
                const uint4v q11 = *(const uint4v*)&xp[a11];
                uint4v pw;
                #pragma unroll
                for (int j = 0; j < 4; ++j) {
                    float2v v = pk_mul(bf2x(q00[j]), w00_2);
                    v = pk_fma(bf2x(q01[j]), w01_2, v);
                    v = pk_fma(bf2x(q10[j]), w10_2, v);
                    v = pk_fma(bf2x(q11[j]), w11_2, v);
                    // round-half-up to bf16 + merge high halves in 1 perm
                    pw[j] = __builtin_amdgcn_perm(
                        __float_as_uint(v.y) + 0x8000u,
                        __float_as_uint(v.x) + 0x8000u,
                        0x07060302u);
                }
                const short8 af = *(const short8*)&pw;
                const int cks = k * 2 + chalf;
                // element ((cks*4+t)*64+lane)*8 = cks*2048 + t*512 + lane*8
                const unsigned short* wb = wtbf + (size_t)cks * 2048 + lane * 8;
                #pragma unroll
                for (int t = 0; t < 4; ++t) {
                    const short8 bfrag = *(const short8*)&wb[(size_t)t * 512];
                    acc[t] = __builtin_amdgcn_mfma_f32_16x16x32_bf16(
                                 af, bfrag, acc[t], 0, 0, 0);
                }
            }
        }
    }

    // ---------------- Epilogue: wave-private staging, coalesced store -------
    // acc[t]: o = t*16+lane15 (col), px16 = quad*4+r (row).
    float* epw = &u.ep[wslot][0][0];
    #pragma unroll
    for (int t = 0; t < 4; ++t)
        #pragma unroll
        for (int r = 0; r < 4; ++r)
            epw[(t * 16 + lane15) * 17 + quad * 4 + r] = acc[t][r];

    const int wo = wo_base + wslot * 16 + lane15;
    #pragma unroll
    for (int i = 0; i < 16; ++i) {
        const int o = i * 4 + quad;
        out[(size_t)(b * O_ + o) * HW_ + ho * W_ + wo] =
            epw[o * 17 + lane15] + bias[o];
    }
}

// ---------------------------------------------------------------------------
extern "C" void kernel_launch(void* const* d_in, const int* in_sizes, int n_in,
                              void* d_out, int out_size, void* d_ws, size_t ws_size,
                              hipStream_t stream) {
    const float* x    = (const float*)d_in[0];  // [4,64,128,128]
    const float* ow   = (const float*)d_in[1];  // [18,64,3,3]
    const float* ob   = (const float*)d_in[2];  // [18]
    const float* w    = (const float*)d_in[3];  // [64,64,3,3]
    const float* bias = (const float*)d_in[4];  // [64]
    float* out = (float*)d_out;                 // [4,64,128,128]

    unsigned short* wtbf  = (unsigned short*)d_ws;      // 4608 frags  73728 B
    unsigned short* owtbf = wtbf + 4608 * 8;            // 2304 frags  36864 B
    unsigned short* xT    = owtbf + 2304 * 8;           // [4][HW][64] 8.39 MB

    prep<<<1051, 256, 0, stream>>>(x, w, ow, xT, wtbf, owtbf);
    dcn_fused<<<B_ * H_ * (W_ / 64), 256, 0, stream>>>(xT, owtbf, ob, wtbf, bias, out);
}

// Round 5
// 110.659 us; speedup vs baseline: 1.1370x; 1.1370x over previous
//
#include <hip/hip_runtime.h>

// Problem constants (B=4, C=64, H=W=128, O=64, K=3, stride=1, pad=1, dil=1)
#define B_   4
#define C_   64
#define O_   64
#define H_   128
#define W_   128
#define HW_  (H_ * W_)
#define KK_  9
#define M_   18          // 2*KK offset channels

typedef short  short8  __attribute__((ext_vector_type(8)));
typedef float  floatx4 __attribute__((ext_vector_type(4)));
typedef float  float2v __attribute__((ext_vector_type(2)));
typedef unsigned int   uint4v   __attribute__((ext_vector_type(4)));
typedef unsigned short ushort8v __attribute__((ext_vector_type(8)));

static __device__ __forceinline__ unsigned short f2bf(float f) {
    unsigned int u = __float_as_uint(f);
    u += 0x7FFFu + ((u >> 16) & 1u);     // round-to-nearest-even
    return (unsigned short)(u >> 16);
}
// unpack a 32-bit word holding 2 bf16 -> v2f32
static __device__ __forceinline__ float2v bf2x(unsigned int q) {
    float2v r;
    r.x = __uint_as_float(q << 16);
    r.y = __uint_as_float(q & 0xFFFF0000u);
    return r;
}
// guaranteed packed fp32 math (VOP3P)
static __device__ __forceinline__ float2v pk_mul(float2v a, float2v b) {
    float2v d;
    asm("v_pk_mul_f32 %0, %1, %2" : "=v"(d) : "v"(a), "v"(b));
    return d;
}
static __device__ __forceinline__ float2v pk_fma(float2v a, float2v b, float2v c) {
    float2v d;
    asm("v_pk_fma_f32 %0, %1, %2, %3" : "=v"(d) : "v"(a), "v"(b), "v"(c));
    return d;
}

// ---------------------------------------------------------------------------
// Prep (single launch):
//  blocks [0,1024):     x -> xT[b][g4][y][x][c16] bf16 (GROUPED layout: 32B
//                       per pixel-group, x-adjacent pixels contiguous ->
//                       gathers span ~half the cache lines vs [c64] layout).
//                       Half-row per block; LDS tile row stride 70 (odd word
//                       count) -> conflict-free column writes.
//  blocks [1024,1042):  wtbf  = main-conv B-fragments in lane order
//                       layout: element ((cks*4 + ot)*64 + lane)*8
//  blocks [1042,1051):  owtbf = offset-conv B-fragments in lane order
// ---------------------------------------------------------------------------
__global__ __launch_bounds__(256) void prep(
        const float* __restrict__ x, const float* __restrict__ w,
        const float* __restrict__ ow, unsigned short* __restrict__ xT,
        unsigned short* __restrict__ wtbf, unsigned short* __restrict__ owtbf) {
    const int blk = blockIdx.x;
    if (blk < 1024) {
        __shared__ unsigned short T[64][70];    // stride 35 words (odd)
        const int tid  = threadIdx.x;
        const int half = blk & 1;
        const int y    = (blk >> 1) & (H_ - 1);
        const int b    = blk >> 8;
        const float* xby = x + (size_t)b * C_ * HW_ + y * W_ + half * 64;
        for (int i = tid; i < 64 * 64; i += 256) {
            const int c = i >> 6, xc = i & 63;
            T[xc][c] = f2bf(xby[(size_t)c * HW_ + xc]);
        }
        __syncthreads();
        // write grouped: xT[((b*4+g)*HW + y*W + x)*16 + sub]
        for (int j = tid; j < 512; j += 256) {
            const int x8 = j >> 3, c8 = j & 7;       // c8 = channel octet
            const int gq  = c8 >> 1;                 // group 0..3
            const int sub = (c8 & 1) * 8;
            uint4v pk;
            #pragma unroll
            for (int k = 0; k < 4; ++k)
                pk[k] = *(const unsigned int*)&T[x8][c8 * 8 + k * 2];
            unsigned short* dst = xT
                + ((size_t)(b * 4 + gq) * HW_ + y * W_ + half * 64 + x8) * 16
                + sub;
            *(uint4v*)dst = pk;
        }
    } else if (blk < 1042) {
        // wtbf: i = (cks*4 + ot)*64 + lane
        const int i = (blk - 1024) * 256 + threadIdx.x;
        const int lane = i & 63, rest = i >> 6;
        const int ot = rest & 3, cks = rest >> 2;      // cks = tap*2+chalf
        const int chunk = cks / 6, ks = cks % 6;
        const int o = ot * 16 + (lane & 15);
        const int kbase = chunk * 192 + ks * 32 + (lane >> 4) * 8;
        ushort8v pk;
        #pragma unroll
        for (int j = 0; j < 8; ++j) {
            const int k = kbase + j;                   // k = tap*64 + c
            pk[j] = f2bf(w[o * 576 + (k & 63) * 9 + (k >> 6)]);
        }
        *(ushort8v*)&wtbf[(size_t)i * 8] = pk;
    } else {
        // owtbf: i = (tks*2 + tile)*64 + lane
        const int i = (blk - 1042) * 256 + threadIdx.x;
        const int lane = i & 63, rest = i >> 6;
        const int tile = rest & 1, tks = rest >> 1;    // tks = tap*2+ks
        const int tap = tks >> 1, ks = tks & 1;
        const int m = tile * 16 + (lane & 15);
        const int cb = ks * 32 + (lane >> 4) * 8;
        ushort8v pk;
        #pragma unroll
        for (int j = 0; j < 8; ++j)
            pk[j] = (m < M_) ? f2bf(ow[m * 576 + (cb + j) * 9 + tap])
                             : (unsigned short)0;
        *(ushort8v*)&owtbf[(size_t)i * 8] = pk;
    }
}

// ---------------------------------------------------------------------------
// Fused deformable conv, 8-WAVE blocks (512 thr) for 100% occupancy:
// wave ws = (p, h): p = px-tile [16p,16p+16), h = tap-half.
//   A1: all 8 waves stage P[3][66][72] from grouped xT          -> barrier
//   A2: h=0 waves compute their tile's 18 offsets via MFMA -> offs[p][18][16]
//                                                               -> barrier
//   B:  wave (p,h) does taps {h, h+2, ...} (parity split), unroll 2.
//       Register-direct A-frags: 4 corner b128 gathers/chalf from grouped xT
//       (x-adjacent px share lines -> ~8 L1 segments/load), packed-fp32
//       bilinear, +0x8000+perm pack, 4 MFMAs vs lane-ordered wtbf.
//   Merge: h1 writes partial acc to ep (dead P union); barrier; h0 adds its
//       acc; barrier; both waves store 32 o-planes each (coalesced).
// Occupancy: 4 blocks/CU x 8 waves = 32 waves/CU (prev 16) -- this kernel is
// gather-latency-bound (r4: MfmaUtil 4.8, VALUBusy 21, occ 36, HBM 5%).
// ---------------------------------------------------------------------------
__global__ __launch_bounds__(512, 8) void dcn_fused(
        const unsigned short* __restrict__ xT,
        const unsigned short* __restrict__ owtbf, const float* __restrict__ ob,
        const unsigned short* __restrict__ wtbf, const float* __restrict__ bias,
        float* __restrict__ out) {
    __shared__ union {
        unsigned short P[3][66][72];             // 28512 B (phase A)
        float ep[4][64][17];                     // 17408 B (merge+epilogue)
    } u;
    __shared__ float offs[4][M_][16];            // 4608 B

    const int tid    = threadIdx.x;
    const int lane   = tid & 63;
    const int ws     = __builtin_amdgcn_readfirstlane(tid >> 6);   // 0..7
    const int p      = ws & 3;                   // px-tile
    const int h      = ws >> 2;                  // tap-half (parity)
    const int lane15 = lane & 15;
    const int quad   = lane >> 4;

    // XCD-banded remap (g%8 = XCD): XCD x -> rows [16x,16x+16), all b/half
    const int g    = blockIdx.x;
    const int xcd  = g & 7;
    const int slot = g >> 3;
    const int ho   = xcd * 16 + (slot >> 3);
    const int b    = (slot >> 1) & 3;
    const int wo_base = (slot & 1) << 6;

    const unsigned short* xTb = xT + (size_t)b * (4 * HW_ * 16);

    // ---------------- Phase A1: stage 3 x-rows into P from xT ----------------
    // P[ky][r][c] = x[c][ho-1+ky][wo_base + r - 1],  r in [0,66)
    #pragma unroll
    for (int ky = 0; ky < 3; ++ky) {
        const int y  = ho - 1 + ky;
        const bool yv = (unsigned)y < (unsigned)H_;
        for (int j = tid; j < 66 * 8; j += 512) {
            const int r = j >> 3, c8 = j & 7;
            const int gq = c8 >> 1, sub = (c8 & 1) * 8;
            const int cx = wo_base + r - 1;
            ushort8v p0 = {0, 0, 0, 0, 0, 0, 0, 0};
            if (yv && (unsigned)cx < (unsigned)W_)
                p0 = *(const ushort8v*)&xTb[(size_t)gq * (HW_ * 16)
                                            + ((size_t)y * W_ + cx) * 16 + sub];
            *(ushort8v*)&u.P[ky][r][c8 * 8] = p0;
        }
    }
    __syncthreads();

    // ---------------- Phase A2: MFMA offset conv (h=0 waves only) -----------
    if (h == 0) {
        floatx4 oa0 = (floatx4){0.f, 0.f, 0.f, 0.f};
        floatx4 oa1 = (floatx4){0.f, 0.f, 0.f, 0.f};
        #pragma unroll
        for (int ky = 0; ky < 3; ++ky) {
            #pragma unroll
            for (int kx = 0; kx < 3; ++kx) {
                const int tap = ky * 3 + kx;
                #pragma unroll
                for (int ks = 0; ks < 2; ++ks) {
                    const int kk = ks * 32 + quad * 8;
                    const short8 af =
                        *(const short8*)&u.P[ky][p * 16 + lane15 + kx][kk];
                    const int fb = ((tap * 2 + ks) * 2) * 64 + lane;
                    const short8 bf0 = *(const short8*)&owtbf[(size_t)fb * 8];
                    const short8 bf1 =
                        *(const short8*)&owtbf[(size_t)(fb + 64) * 8];
                    oa0 = __builtin_amdgcn_mfma_f32_16x16x32_bf16(af, bf0, oa0, 0, 0, 0);
                    oa1 = __builtin_amdgcn_mfma_f32_16x16x32_bf16(af, bf1, oa1, 0, 0, 0);
                }
            }
        }
        const float ob0 = ob[lane15];
        #pragma unroll
        for (int r = 0; r < 4; ++r) oa0[r] += ob0;
        *(floatx4*)&offs[p][lane15][quad * 4] = oa0;
        if (lane15 < 2) {
            const float ob1 = ob[16 + lane15];
            #pragma unroll
            for (int r = 0; r < 4; ++r) oa1[r] += ob1;
            *(floatx4*)&offs[p][16 + lane15][quad * 4] = oa1;
        }
    }
    __syncthreads();   // offs visible to all; P now dead -> ep may be used

    // ---------------- Phase B: parity-split taps, register-direct A-frags ---
    const int pxg = p * 16 + lane15;       // px within the 64-px segment
    floatx4 acc[4];                        // o-tiles 0..3 (partial over taps)
    #pragma unroll
    for (int t = 0; t < 4; ++t) acc[t] = (floatx4){0.f, 0.f, 0.f, 0.f};

    #pragma unroll 2
    for (int k = h; k < 9; k += 2) {       // h0: 0,2,4,6,8; h1: 1,3,5,7
        const int ky = k / 3, kx = k - ky * 3;
        const float offy = offs[p][2 * k][lane15];
        const float offx = offs[p][2 * k + 1][lane15];
        const float py  = (float)(ho - 1 + ky) + offy;
        const float pxx = (float)(wo_base - 1 + kx + pxg) + offx;
        const float fy = floorf(py), fx = floorf(pxx);
        const int y0 = (int)fy, x0 = (int)fx;
        const int y1 = y0 + 1,  x1 = x0 + 1;
        const float wy1 = py - fy,  wy0 = 1.f - wy1;
        const float wx1 = pxx - fx, wx0 = 1.f - wx1;
        const bool y0v = (unsigned)y0 < (unsigned)H_;
        const bool y1v = (unsigned)y1 < (unsigned)H_;
        const bool x0v = (unsigned)x0 < (unsigned)W_;
        const bool x1v = (unsigned)x1 < (unsigned)W_;
        const float w00 = (y0v && x0v) ? wy0 * wx0 : 0.f;
        const float w01 = (y0v && x1v) ? wy0 * wx1 : 0.f;
        const float w10 = (y1v && x0v) ? wy1 * wx0 : 0.f;
        const float w11 = (y1v && x1v) ? wy1 * wx1 : 0.f;
        const float2v w00_2 = {w00, w00};
        const float2v w01_2 = {w01, w01};
        const float2v w10_2 = {w10, w10};
        const float2v w11_2 = {w11, w11};
        const int ry0 = min(max(y0, 0), H_ - 1);
        const int ry1 = min(max(y1, 0), H_ - 1);
        const int cx0 = min(max(x0, 0), W_ - 1);
        const int cx1 = min(max(x1, 0), W_ - 1);
        const int a00 = (ry0 * W_ + cx0) * 16;   // ushort idx in a g-plane
        const int a01 = (ry0 * W_ + cx1) * 16;
        const int a10 = (ry1 * W_ + cx0) * 16;
        const int a11 = (ry1 * W_ + cx1) * 16;
        #pragma unroll
        for (int chalf = 0; chalf < 2; ++chalf) {
            // lane's channel octet c0 lives in g-plane c0>>4 at byte (c0&8)*2
            const int c0 = chalf * 32 + quad * 8;
            const unsigned short* xp =
                xTb + (size_t)(c0 >> 4) * (HW_ * 16) + (c0 & 8);
            const uint4v q00 = *(const uint4v*)&xp[a00];
            const uint4v q01 = *(const uint4v*)&xp[a01];
            const uint4v q10 = *(const uint4v*)&xp[a10];
            const uint4v q11 = *(const uint4v*)&xp[a11];
            uint4v pw;
            #pragma unroll
            for (int j = 0; j < 4; ++j) {
                float2v v = pk_mul(bf2x(q00[j]), w00_2);
                v = pk_fma(bf2x(q01[j]), w01_2, v);
                v = pk_fma(bf2x(q10[j]), w10_2, v);
                v = pk_fma(bf2x(q11[j]), w11_2, v);
                pw[j] = __builtin_amdgcn_perm(
                    __float_as_uint(v.y) + 0x8000u,
                    __float_as_uint(v.x) + 0x8000u,
                    0x07060302u);
            }
            const short8 af = *(const short8*)&pw;
            const int cks = k * 2 + chalf;
            // element ((cks*4+t)*64+lane)*8 = cks*2048 + t*512 + lane*8
            const unsigned short* wb = wtbf + (size_t)cks * 2048 + lane * 8;
            #pragma unroll
            for (int t = 0; t < 4; ++t) {
                const short8 bfrag = *(const short8*)&wb[(size_t)t * 512];
                acc[t] = __builtin_amdgcn_mfma_f32_16x16x32_bf16(
                             af, bfrag, acc[t], 0, 0, 0);
            }
        }
    }

    // ---------------- Merge halves + epilogue -------------------------------
    // acc[t]: o = t*16+lane15 (col), px16 = quad*4+r (row).
    float* epw = &u.ep[p][0][0];
    if (h == 1) {
        #pragma unroll
        for (int t = 0; t < 4; ++t)
            #pragma unroll
            for (int r = 0; r < 4; ++r)
                epw[(t * 16 + lane15) * 17 + quad * 4 + r] = acc[t][r];
    }
    __syncthreads();
    if (h == 0) {
        #pragma unroll
        for (int t = 0; t < 4; ++t)
            #pragma unroll
            for (int r = 0; r < 4; ++r)
                epw[(t * 16 + lane15) * 17 + quad * 4 + r] += acc[t][r];
    }
    __syncthreads();

    const int wo = wo_base + p * 16 + lane15;
    #pragma unroll
    for (int i = 0; i < 8; ++i) {
        const int o = (h * 8 + i) * 4 + quad;    // each h-wave: 32 o-planes
        out[(size_t)(b * O_ + o) * HW_ + ho * W_ + wo] =
            epw[o * 17 + lane15] + bias[o];
    }
}

// ---------------------------------------------------------------------------
extern "C" void kernel_launch(void* const* d_in, const int* in_sizes, int n_in,
                              void* d_out, int out_size, void* d_ws, size_t ws_size,
                              hipStream_t stream) {
    const float* x    = (const float*)d_in[0];  // [4,64,128,128]
    const float* ow   = (const float*)d_in[1];  // [18,64,3,3]
    const float* ob   = (const float*)d_in[2];  // [18]
    const float* w    = (const float*)d_in[3];  // [64,64,3,3]
    const float* bias = (const float*)d_in[4];  // [64]
    float* out = (float*)d_out;                 // [4,64,128,128]

    unsigned short* wtbf  = (unsigned short*)d_ws;      // 4608 frags  73728 B
    unsigned short* owtbf = wtbf + 4608 * 8;            // 2304 frags  36864 B
    unsigned short* xT    = owtbf + 2304 * 8;           // [4][4][HW][16] 8.39 MB

    prep<<<1051, 256, 0, stream>>>(x, w, ow, xT, wtbf, owtbf);
    dcn_fused<<<B_ * H_ * (W_ / 64), 512, 0, stream>>>(xT, owtbf, ob, wtbf, bias, out);
}